// Round 9
// baseline (14418.059 us; speedup 1.0000x reference)
//
#include <hip/hip_runtime.h>
#include <math.h>

#define HH 1024
#define VV 4096
#define TSTEPS 128
#define NB 256
#define NT 512

typedef float  floatx4 __attribute__((ext_vector_type(4)));
typedef float  floatx2 __attribute__((ext_vector_type(2)));
typedef int    intx4   __attribute__((ext_vector_type(4)));

// ---------- helpers ----------

__device__ __forceinline__ float sigf(float x) { return 1.0f / (1.0f + expf(-x)); }

// sum across each 16-lane row via DPP; row total lands in lane (row*16+15).
__device__ __forceinline__ float rowsum16(float x) {
  x += __int_as_float(__builtin_amdgcn_update_dpp(0, __float_as_int(x), 0x111, 0xf, 0xf, true));
  x += __int_as_float(__builtin_amdgcn_update_dpp(0, __float_as_int(x), 0x112, 0xf, 0xf, true));
  x += __int_as_float(__builtin_amdgcn_update_dpp(0, __float_as_int(x), 0x114, 0xf, 0xf, true));
  x += __int_as_float(__builtin_amdgcn_update_dpp(0, __float_as_int(x), 0x118, 0xf, 0xf, true));
  return x;
}

// descending top-5 insert, tie -> lower flat index (matches jax.lax.top_k)
__device__ __forceinline__ void ins5(float* bv, int* bi, float v, int i) {
#pragma unroll
  for (int j = 0; j < 5; ++j) {
    if (v > bv[j] || (v == bv[j] && i < bi[j])) {
#pragma unroll
      for (int s = 4; s > j; --s) { bv[s] = bv[s - 1]; bi[s] = bi[s - 1]; }
      bv[j] = v; bi[j] = i;
      break;
    }
  }
}

// ---------- coherence tiers ----------
// sc0 sc1 : LLC-coherent (cross-XCD). Writers write through; readers bypass
//           L1+L2. Used ONLY for data that must cross XCDs.
// sc0     : within-XCD. Bypasses L1 only; served by the XCD's own L2.
//           Used for the per-XCD staged activation broadcast (round-8 lesson:
//           LLC can't serve 256-way duplicate bypass reads; L2 dedups 32x).
// All loads BLOCKING (waitcnt inside asm) - round-3 lesson.

__device__ __forceinline__ float ldcc(const float* p) {
  float v;
  asm volatile("global_load_dword %0, %1, off sc0 sc1\n\ts_waitcnt vmcnt(0)"
               : "=&v"(v) : "v"(p) : "memory");
  return v;
}
__device__ __forceinline__ int ldcci(const int* p) {
  int v;
  asm volatile("global_load_dword %0, %1, off sc0 sc1\n\ts_waitcnt vmcnt(0)"
               : "=&v"(v) : "v"(p) : "memory");
  return v;
}
__device__ __forceinline__ floatx4 ldcc4(const float* p) {
  floatx4 v;
  asm volatile("global_load_dwordx4 %0, %1, off sc0 sc1\n\ts_waitcnt vmcnt(0)"
               : "=&v"(v) : "v"(p) : "memory");
  return v;
}
__device__ __forceinline__ void stcc(float* p, float v) {
  asm volatile("global_store_dword %0, %1, off sc0 sc1" :: "v"(p), "v"(v) : "memory");
}
__device__ __forceinline__ void stcci(int* p, int v) {
  asm volatile("global_store_dword %0, %1, off sc0 sc1" :: "v"(p), "v"(v) : "memory");
}
__device__ __forceinline__ void stcc4(float* p, floatx4 v) {
  asm volatile("global_store_dwordx4 %0, %1, off sc0 sc1" :: "v"(p), "v"(v) : "memory");
}
__device__ __forceinline__ void stcc4i(int* p, intx4 v) {
  asm volatile("global_store_dwordx4 %0, %1, off sc0 sc1" :: "v"(p), "v"(v) : "memory");
}

// within-XCD (L2-served) loads
__device__ __forceinline__ float ldl2(const float* p) {
  float v;
  asm volatile("global_load_dword %0, %1, off sc0\n\ts_waitcnt vmcnt(0)"
               : "=&v"(v) : "v"(p) : "memory");
  return v;
}
__device__ __forceinline__ void ldl2x5(const float* p0, const float* p1, const float* p2,
                                       const float* p3, const float* p4,
                                       floatx4& v0, floatx4& v1, floatx4& v2,
                                       floatx4& v3, floatx4& v4) {
  asm volatile(
      "global_load_dwordx4 %0, %5, off sc0\n\t"
      "global_load_dwordx4 %1, %6, off sc0\n\t"
      "global_load_dwordx4 %2, %7, off sc0\n\t"
      "global_load_dwordx4 %3, %8, off sc0\n\t"
      "global_load_dwordx4 %4, %9, off sc0\n\t"
      "s_waitcnt vmcnt(0)"
      : "=&v"(v0), "=&v"(v1), "=&v"(v2), "=&v"(v3), "=&v"(v4)
      : "v"(p0), "v"(p1), "v"(p2), "v"(p3), "v"(p4)
      : "memory");
}

// two 8B LLC-bypass loads, one latency (XCD-staging gather)
__device__ __forceinline__ void ldcc2x2(const float* p0, const float* p1,
                                        floatx2& a, floatx2& b) {
  asm volatile(
      "global_load_dwordx2 %0, %2, off sc0 sc1\n\t"
      "global_load_dwordx2 %1, %3, off sc0 sc1\n\t"
      "s_waitcnt vmcnt(0)"
      : "=&v"(a), "=&v"(b) : "v"(p0), "v"(p1) : "memory");
}
__device__ __forceinline__ floatx2 ldcc2(const float* p) {
  floatx2 v;
  asm volatile("global_load_dwordx2 %0, %1, off sc0 sc1\n\ts_waitcnt vmcnt(0)"
               : "=&v"(v) : "v"(p) : "memory");
  return v;
}

// persistent-weight load: NORMAL cached load via asm volatile so the compiler
// can neither rematerialize nor sink it into the t-loop.
__device__ __forceinline__ void ldwt(floatx4& v, const float* p) {
  asm volatile("global_load_dwordx4 %0, %1, off\n\ts_waitcnt vmcnt(0)"
               : "=&v"(v) : "v"(p));
}

// top5 record (5 floats + 5 ints, stride-8 padded), one latency.
__device__ __forceinline__ void ldcc_top5(const float* pv, const int* pi,
                                          float tv[5], int ti[5]) {
  floatx4 a; float a1; intx4 b; int b1;
  asm volatile(
      "global_load_dwordx4 %0, %4, off sc0 sc1\n\t"
      "global_load_dword   %1, %5, off sc0 sc1\n\t"
      "global_load_dwordx4 %2, %6, off sc0 sc1\n\t"
      "global_load_dword   %3, %7, off sc0 sc1\n\t"
      "s_waitcnt vmcnt(0)"
      : "=&v"(a), "=&v"(a1), "=&v"(b), "=&v"(b1)
      : "v"(pv), "v"(pv + 4), "v"(pi), "v"(pi + 4)
      : "memory");
  tv[0] = a.x; tv[1] = a.y; tv[2] = a.z; tv[3] = a.w; tv[4] = a1;
  ti[0] = b.x; ti[1] = b.y; ti[2] = b.z; ti[3] = b.w; ti[4] = b1;
}

// beam-state record (1 float + 4 ints), one latency.
__device__ __forceinline__ void ldcc_state(const float* ps, const int* pl, const int* pt,
                                           const int* pp, const int* pb,
                                           float& sc, int& ln, int& tk, int& pr, int& bl) {
  asm volatile(
      "global_load_dword %0, %5, off sc0 sc1\n\t"
      "global_load_dword %1, %6, off sc0 sc1\n\t"
      "global_load_dword %2, %7, off sc0 sc1\n\t"
      "global_load_dword %3, %8, off sc0 sc1\n\t"
      "global_load_dword %4, %9, off sc0 sc1\n\t"
      "s_waitcnt vmcnt(0)"
      : "=&v"(sc), "=&v"(ln), "=&v"(tk), "=&v"(pr), "=&v"(bl)
      : "v"(ps), "v"(pl), "v"(pt), "v"(pp), "v"(pb)
      : "memory");
}

// ---------- setup kernels ----------

// out[C][R] = in[R][C]
__global__ __launch_bounds__(256) void k_transp(const float* __restrict__ in,
                                                float* __restrict__ out, int R, int C) {
  __shared__ float tile[32][33];
  int c0 = blockIdx.x * 32, r0 = blockIdx.y * 32;
  int tx = threadIdx.x & 31, ty = threadIdx.x >> 5;
#pragma unroll
  for (int i = 0; i < 32; i += 8) tile[ty + i][tx] = in[(long)(r0 + ty + i) * C + c0 + tx];
  __syncthreads();
#pragma unroll
  for (int i = 0; i < 32; i += 8) out[(long)(c0 + ty + i) * R + r0 + tx] = tile[tx][ty + i];
}

// C[1024,1024] = A[1024,1024] @ B[1024,1024]   (tn_proj = tn_output @ W_tn)
__global__ __launch_bounds__(256) void k_tnproj(const float* __restrict__ A,
                                                const float* __restrict__ B,
                                                float* __restrict__ C) {
  __shared__ float As[64][20];
  __shared__ float Bs[16][68];
  int tid = threadIdx.x, blk = blockIdx.x;
  int bx = blk & 15, by = blk >> 4;
  int tx = tid & 15, ty = tid >> 4;
  float acc[4][4];
#pragma unroll
  for (int i = 0; i < 4; i++)
#pragma unroll
    for (int j = 0; j < 4; j++) acc[i][j] = 0.f;
  for (int k0 = 0; k0 < 1024; k0 += 16) {
    {
      int row = tid >> 2, q = tid & 3;
      float4 v = *(const float4*)&A[(long)(by * 64 + row) * 1024 + k0 + q * 4];
      As[row][q * 4] = v.x; As[row][q * 4 + 1] = v.y; As[row][q * 4 + 2] = v.z; As[row][q * 4 + 3] = v.w;
    }
    {
      int row = tid >> 4, q = tid & 15;
      float4 v = *(const float4*)&B[(long)(k0 + row) * 1024 + bx * 64 + q * 4];
      *(float4*)&Bs[row][q * 4] = v;
    }
    __syncthreads();
#pragma unroll
    for (int kk = 0; kk < 16; kk++) {
      float a0 = As[ty * 4][kk], a1 = As[ty * 4 + 1][kk], a2 = As[ty * 4 + 2][kk], a3 = As[ty * 4 + 3][kk];
      float4 b4 = *(const float4*)&Bs[kk][tx * 4];
      acc[0][0] += a0 * b4.x; acc[0][1] += a0 * b4.y; acc[0][2] += a0 * b4.z; acc[0][3] += a0 * b4.w;
      acc[1][0] += a1 * b4.x; acc[1][1] += a1 * b4.y; acc[1][2] += a1 * b4.z; acc[1][3] += a1 * b4.w;
      acc[2][0] += a2 * b4.x; acc[2][1] += a2 * b4.y; acc[2][2] += a2 * b4.z; acc[2][3] += a2 * b4.w;
      acc[3][0] += a3 * b4.x; acc[3][1] += a3 * b4.y; acc[3][2] += a3 * b4.z; acc[3][3] += a3 * b4.w;
    }
    __syncthreads();
  }
#pragma unroll
  for (int i = 0; i < 4; i++) {
    float4 v = make_float4(acc[i][0], acc[i][1], acc[i][2], acc[i][3]);
    *(float4*)&C[(long)(by * 64 + ty * 4 + i) * 1024 + bx * 64 + tx * 4] = v;
  }
}

// ---------- persistent megakernel ----------
// 256 blocks x 512 thr, cooperative. Weights pinned via asm-volatile loads.
// Per phase, each XCD's blocks gather the 40 activation rows ONCE from the
// LLC into a per-XCD scratch buffer (plain stores -> own L2), cross a
// per-XCD barrier, then all blocks read the staged copy with sc0 loads
// (L2-served broadcast). Cross-XCD hand-off stays sc0/sc1 + fence-free gsync.

__global__ __launch_bounds__(NT, 1) void k_beam(
    const float* __restrict__ E, const float* __restrict__ Wih,
    const float* __restrict__ Whh, const float* __restrict__ b_lstm,
    const float* __restrict__ tn_proj, const float* __restrict__ WpnT,
    const float* __restrict__ b_joint, const float* __restrict__ WoutT,
    const float* __restrict__ b_out,
    float* __restrict__ h_pre0, float* __restrict__ h_pre1,
    float* __restrict__ c_pre0, float* __restrict__ c_pre1,
    float* __restrict__ h_new0, float* __restrict__ h_new1,
    float* __restrict__ c_new0, float* __restrict__ c_new1,
    float* __restrict__ joint, float* __restrict__ expsum_part,
    float* __restrict__ top5v, int* __restrict__ top5i,
    int* __restrict__ preds0, int* __restrict__ preds1,
    float* __restrict__ gscores, int* __restrict__ glens,
    int* __restrict__ gtokens, int* __restrict__ gpar, int* __restrict__ gblank,
    float* __restrict__ xcdbufA, float* __restrict__ xcdbufB,
    unsigned int* bar, float* __restrict__ out) {
  int tid = threadIdx.x, blk = blockIdx.x;
  int wav = tid >> 6, lane = tid & 63;

  __shared__ float xs[10240];           // 40 KB staging (union G/J/L)
  __shared__ float part[640];
  __shared__ float s_scores[40], s_scls[5];
  __shared__ int s_tokens[40], s_lens[40], s_par[40], s_blank[40];
  __shared__ float s_csel[160];         // prefetched c-state for G finish
  __shared__ float wtv[40];
  __shared__ int wti[40];
  __shared__ int s_best[8];
  __shared__ float s_maxn[8];
  __shared__ int s_xrank, s_xn;
  float4* xs4 = (float4*)xs;

  // physical XCD of this block (wave-uniform; all waves same CU)
  int xcd;
  asm("s_getreg_b32 %0, hwreg(HW_REG_XCC_ID)" : "=s"(xcd));
  xcd &= 7;
  float* xcdA = xcdbufA + (long)xcd * 40960;   // staged h rows [40][1024]
  float* xcdB = xcdbufB + (long)xcd * 40960;   // staged c rows [40][1024]

  // ---- persistent register-resident weights (112 VGPRs, asm-pinned) ----
  floatx4 wihr[2][4], whhr[2][4], wpnr[4], woutr[2][4];
#pragma unroll
  for (int rr = 0; rr < 2; ++rr) {
    int gr = wav * 2 + rr;
    int jg = blk * 4 + (gr >> 2), g = gr & 3;
#pragma unroll
    for (int c = 0; c < 4; ++c) {
      ldwt(wihr[rr][c], &Wih[(long)(g * HH + jg) * HH + c * 256 + lane * 4]);
      ldwt(whhr[rr][c], &Whh[(long)(g * HH + jg) * HH + c * 256 + lane * 4]);
    }
  }
  {
    int d = blk * 4 + (wav >> 1);       // two waves per d-row (m-halves)
#pragma unroll
    for (int c = 0; c < 4; ++c)
      ldwt(wpnr[c], &WpnT[(long)d * HH + c * 256 + lane * 4]);
  }
#pragma unroll
  for (int r = 0; r < 2; ++r) {
    int v = blk * 16 + wav * 2 + r;
#pragma unroll
    for (int c = 0; c < 4; ++c)
      ldwt(woutr[r][c], &WoutT[(long)v * HH + c * 256 + lane * 4]);
  }

  if (tid < 40) {
    s_scores[tid] = ((tid % 5) == 0) ? 0.f : -1e9f;
    s_tokens[tid] = 0; s_lens[tid] = 0; s_par[tid] = tid; s_blank[tid] = 1;
  }
  // register with this XCD (dynamic membership; mapping-agnostic)
  if (tid == 0)
    s_xrank = (int)__hip_atomic_fetch_add(&bar[256 + xcd], 1u,
                                          __ATOMIC_RELAXED, __HIP_MEMORY_SCOPE_AGENT);
  __syncthreads();

  unsigned int round = 0;
  // fence-free global barrier: vmcnt(0) drains all (coherent) stores; the
  // relaxed agent atomics live at the LLC; consumers re-read via sc0/sc1.
  auto gsync = [&]() {
    asm volatile("s_waitcnt vmcnt(0)" ::: "memory");
    __syncthreads();
    if (tid == 0)
      __hip_atomic_fetch_add(&bar[(blk & 15) * 16], 1u, __ATOMIC_RELAXED, __HIP_MEMORY_SCOPE_AGENT);
    ++round;
    if (tid < 16) {
      unsigned int tgt = round * 16u;
      while (__hip_atomic_load(&bar[tid * 16], __ATOMIC_RELAXED, __HIP_MEMORY_SCOPE_AGENT) < tgt)
        __builtin_amdgcn_s_sleep(2);
    }
    __syncthreads();
  };

  // per-XCD barrier: all blocks of this XCD; staged L2 data becomes visible
  // (writers' stores drained by vmcnt(0); readers use sc0 loads).
  unsigned int xround = 0;
  auto xsync = [&]() {
    asm volatile("s_waitcnt vmcnt(0)" ::: "memory");
    __syncthreads();
    if (tid == 0)
      __hip_atomic_fetch_add(&bar[320 + xcd * 16], 1u, __ATOMIC_RELAXED, __HIP_MEMORY_SCOPE_AGENT);
    ++xround;
    if (tid == 0) {
      unsigned int tgt = xround * (unsigned int)s_xn;
      while (__hip_atomic_load(&bar[320 + xcd * 16], __ATOMIC_RELAXED, __HIP_MEMORY_SCOPE_AGENT) < tgt)
        __builtin_amdgcn_s_sleep(2);
    }
    __syncthreads();
  };

  // finish registration: one global barrier, then read membership count
  gsync();
  if (tid == 0)
    s_xn = (int)__hip_atomic_load(&bar[256 + xcd], __ATOMIC_RELAXED, __HIP_MEMORY_SCOPE_AGENT);
  __syncthreads();
  int xrank = s_xrank, xn = s_xn;

  auto preds_update = [&](int u) {   // blk<4 only; rows blk*10..+9
    const int* pip = ((u - 1) & 1) ? preds1 : preds0;
    int* pop = (u & 1) ? preds1 : preds0;
    int m0 = blk * 10;
    for (int cell = tid; cell < 1280; cell += NT) {
      int j = cell >> 7, pos = cell & 127, gj = m0 + j;
      int isb = s_blank[gj];
      int plen = s_lens[gj] - (isb ? 0 : 1);
      int v = ldcci(&pip[s_par[gj] * 128 + pos]);
      if (!isb && pos == plen) v = s_tokens[gj];
      stcci(&pop[gj * 128 + pos], v);
    }
  };

  int mat = tid >> 8, k4f = (tid & 255) * 4;   // staging role, per-thread constant
  int seg = tid * 2;                           // XCD-staging: 2 floats/thread

  for (int t = 0; t < TSTEPS; ++t) {
    const float* h_pre_in = (t & 1) ? h_pre1 : h_pre0;
    const float* h_new_in = (t & 1) ? h_new1 : h_new0;
    const float* c_pre_in = (t & 1) ? c_pre1 : c_pre0;
    const float* c_new_in = (t & 1) ? c_new1 : c_new0;
    float* h_pre_o = (t & 1) ? h_pre0 : h_pre1;
    float* h_new_o = (t & 1) ? h_new0 : h_new1;
    float* c_pre_o = (t & 1) ? c_pre0 : c_pre1;
    float* c_new_o = (t & 1) ? c_new0 : c_new1;

    if (t > 0) {   // load beam state published by M of step t-1
      if (tid < 40) {
        float sc; int ln, tk, pr, bl;
        ldcc_state(&gscores[tid], &glens[tid], &gtokens[tid], &gpar[tid], &gblank[tid],
                   sc, ln, tk, pr, bl);
        s_scores[tid] = sc; s_lens[tid] = ln; s_tokens[tid] = tk;
        s_par[tid] = pr; s_blank[tid] = bl;
      }
      __syncthreads();
      // ---- XCD staging: gather selected h and c rows ONCE per XCD ----
      for (int row = xrank; row < 40; row += xn) {
        const float* hb = s_blank[row] ? h_pre_in : h_new_in;
        const float* cb = s_blank[row] ? c_pre_in : c_new_in;
        long so = (long)s_par[row] * HH + seg;
        floatx2 hv, cv2;
        ldcc2x2(&hb[so], &cb[so], hv, cv2);
        *(floatx2*)&xcdA[row * HH + seg] = hv;
        *(floatx2*)&xcdB[row * HH + seg] = cv2;
      }
      if (blk < 4) preds_update(t);
      xsync();
      // c-state for G finish, from per-XCD staged copy (L2-served)
      if (tid < 160) {
        int mg = tid >> 2, j = tid & 3;
        s_csel[tid] = ldl2(&xcdB[mg * HH + blk * 4 + j]);
      }
    }

    // ---- phase G: gates + cell for all 40 hyps, 8 staggered chunks of 5 ----
    {
      for (int cc = 0; cc < 8; ++cc) {
        int ch = (blk + cc) & 7;
        int mbase = ch * 5;
        if (mat == 0) {                 // E rows: read-only cached loads
#pragma unroll
          for (int i = 0; i < 5; ++i)
            xs4[i * 512 + tid] = *(const float4*)&E[(long)s_tokens[mbase + i] * HH + k4f];
        } else if (t == 0) {
          floatx4 z = {0.f, 0.f, 0.f, 0.f};
#pragma unroll
          for (int i = 0; i < 5; ++i) {
            *(floatx4*)(xs4 + i * 512 + tid) = z;
            if (blk == ch) stcc4(&h_pre_o[(long)(mbase + i) * HH + k4f], z);
          }
        } else {                        // h rows: L2-served staged broadcast
          floatx4 v0, v1, v2, v3, v4;
          ldl2x5(&xcdA[(mbase + 0) * HH + k4f], &xcdA[(mbase + 1) * HH + k4f],
                 &xcdA[(mbase + 2) * HH + k4f], &xcdA[(mbase + 3) * HH + k4f],
                 &xcdA[(mbase + 4) * HH + k4f], v0, v1, v2, v3, v4);
          *(floatx4*)(xs4 + 0 * 512 + tid) = v0;
          *(floatx4*)(xs4 + 1 * 512 + tid) = v1;
          *(floatx4*)(xs4 + 2 * 512 + tid) = v2;
          *(floatx4*)(xs4 + 3 * 512 + tid) = v3;
          *(floatx4*)(xs4 + 4 * 512 + tid) = v4;
          if (blk == ch) {              // exclusive owner publishes h_pre
            stcc4(&h_pre_o[(long)(mbase + 0) * HH + k4f], v0);
            stcc4(&h_pre_o[(long)(mbase + 1) * HH + k4f], v1);
            stcc4(&h_pre_o[(long)(mbase + 2) * HH + k4f], v2);
            stcc4(&h_pre_o[(long)(mbase + 3) * HH + k4f], v3);
            stcc4(&h_pre_o[(long)(mbase + 4) * HH + k4f], v4);
          }
        }
        __syncthreads();
        float acc[5][2];
#pragma unroll
        for (int m = 0; m < 5; ++m) { acc[m][0] = 0.f; acc[m][1] = 0.f; }
#pragma unroll
        for (int m = 0; m < 5; ++m) {
#pragma unroll
          for (int c = 0; c < 4; ++c) {
            float4 x = xs4[m * 512 + c * 64 + lane];
#pragma unroll
            for (int rr = 0; rr < 2; ++rr) {
              floatx4 ww = wihr[rr][c];
              acc[m][rr] += x.x * ww.x; acc[m][rr] += x.y * ww.y;
              acc[m][rr] += x.z * ww.z; acc[m][rr] += x.w * ww.w;
            }
          }
#pragma unroll
          for (int c = 0; c < 4; ++c) {
            float4 x = xs4[m * 512 + 256 + c * 64 + lane];
#pragma unroll
            for (int rr = 0; rr < 2; ++rr) {
              floatx4 ww = whhr[rr][c];
              acc[m][rr] += x.x * ww.x; acc[m][rr] += x.y * ww.y;
              acc[m][rr] += x.z * ww.z; acc[m][rr] += x.w * ww.w;
            }
          }
        }
#pragma unroll
        for (int m = 0; m < 5; ++m) {
          acc[m][0] = rowsum16(acc[m][0]);
          acc[m][1] = rowsum16(acc[m][1]);
        }
        if ((lane & 15) == 15) {
          int grp = lane >> 4;
#pragma unroll
          for (int m = 0; m < 5; ++m) {
            part[(wav * 4 + grp) * 10 + m * 2] = acc[m][0];
            part[(wav * 4 + grp) * 10 + m * 2 + 1] = acc[m][1];
          }
        }
        __syncthreads();
        if (tid < 20) {
          int mloc = tid >> 2, j = tid & 3;
          int mg = mbase + mloc, jglob = blk * 4 + j;
          float gi = 0.f, gf = 0.f, gg = 0.f, go = 0.f;
#pragma unroll
          for (int r = 0; r < 4; ++r) {
            gi += part[((j * 2) * 4 + r) * 10 + mloc * 2];
            gf += part[((j * 2) * 4 + r) * 10 + mloc * 2 + 1];
            gg += part[((j * 2 + 1) * 4 + r) * 10 + mloc * 2];
            go += part[((j * 2 + 1) * 4 + r) * 10 + mloc * 2 + 1];
          }
          gi += b_lstm[jglob]; gf += b_lstm[HH + jglob];
          gg += b_lstm[2 * HH + jglob]; go += b_lstm[3 * HH + jglob];
          float csel = (t == 0) ? 0.f : s_csel[mg * 4 + j];
          float cn = sigf(gf) * csel + sigf(gi) * tanhf(gg);
          float hn = sigf(go) * tanhf(cn);
          long o = (long)mg * HH + jglob;
          stcc(&h_new_o[o], hn); stcc(&c_new_o[o], cn); stcc(&c_pre_o[o], csel);
        }
      }
    }
    gsync();

    // ---- phase J: joint = tanh(tn + h_new @ W_pn + b), 4 staggered chunks ----
    {
      // XCD staging of h_new rows
      for (int row = xrank; row < 40; row += xn) {
        floatx2 v = ldcc2(&h_new_o[(long)row * HH + seg]);
        *(floatx2*)&xcdA[row * HH + seg] = v;
      }
      xsync();
      int mrow = mat;
      for (int cc = 0; cc < 4; ++cc) {
        int ch = (blk + cc) & 3;
        int mbase = ch * 10;
        floatx4 v0, v1, v2, v3, v4;
        ldl2x5(&xcdA[(mbase + mrow + 0) * HH + k4f],
               &xcdA[(mbase + mrow + 2) * HH + k4f],
               &xcdA[(mbase + mrow + 4) * HH + k4f],
               &xcdA[(mbase + mrow + 6) * HH + k4f],
               &xcdA[(mbase + mrow + 8) * HH + k4f],
               v0, v1, v2, v3, v4);
        *(floatx4*)(xs4 + 0 * 512 + tid) = v0;
        *(floatx4*)(xs4 + 1 * 512 + tid) = v1;
        *(floatx4*)(xs4 + 2 * 512 + tid) = v2;
        *(floatx4*)(xs4 + 3 * 512 + tid) = v3;
        *(floatx4*)(xs4 + 4 * 512 + tid) = v4;
        __syncthreads();
        float accj[5];
#pragma unroll
        for (int m = 0; m < 5; ++m) accj[m] = 0.f;
        int mh = (wav & 1) * 5;
#pragma unroll
        for (int m = 0; m < 5; ++m) {
#pragma unroll
          for (int c = 0; c < 4; ++c) {
            float4 x = xs4[(mh + m) * 256 + c * 64 + lane];
            floatx4 ww = wpnr[c];
            accj[m] += x.x * ww.x; accj[m] += x.y * ww.y;
            accj[m] += x.z * ww.z; accj[m] += x.w * ww.w;
          }
        }
#pragma unroll
        for (int m = 0; m < 5; ++m) accj[m] = rowsum16(accj[m]);
        if ((lane & 15) == 15) {
          int grp = lane >> 4;
#pragma unroll
          for (int m = 0; m < 5; ++m) part[(wav * 4 + grp) * 5 + m] = accj[m];
        }
        __syncthreads();
        if (tid < 40) {
          int mloc = tid >> 2, d = tid & 3;
          int wv = d * 2 + (mloc >= 5 ? 1 : 0), m5 = mloc % 5;
          float s = 0.f;
#pragma unroll
          for (int r = 0; r < 4; ++r) s += part[(wv * 4 + r) * 5 + m5];
          int mg = mbase + mloc, dglob = blk * 4 + d, b = mg / 5;
          stcc(&joint[(long)mg * HH + dglob],
               tanhf(s + tn_proj[((long)b * TSTEPS + t) * HH + dglob] + b_joint[dglob]));
        }
      }
    }
    gsync();

    // ---- phase L: logits + per-(m,blk) exp-sum partial + local top-5 of 16 ----
    {
      // XCD staging of joint rows
      for (int row = xrank; row < 40; row += xn) {
        floatx2 v = ldcc2(&joint[(long)row * HH + seg]);
        *(floatx2*)&xcdA[row * HH + seg] = v;
      }
      xsync();
      int mrow = mat;
      for (int cc = 0; cc < 4; ++cc) {
        int ch = (blk + cc) & 3;
        int mbase = ch * 10;
        floatx4 v0, v1, v2, v3, v4;
        ldl2x5(&xcdA[(mbase + mrow + 0) * HH + k4f],
               &xcdA[(mbase + mrow + 2) * HH + k4f],
               &xcdA[(mbase + mrow + 4) * HH + k4f],
               &xcdA[(mbase + mrow + 6) * HH + k4f],
               &xcdA[(mbase + mrow + 8) * HH + k4f],
               v0, v1, v2, v3, v4);
        *(floatx4*)(xs4 + 0 * 512 + tid) = v0;
        *(floatx4*)(xs4 + 1 * 512 + tid) = v1;
        *(floatx4*)(xs4 + 2 * 512 + tid) = v2;
        *(floatx4*)(xs4 + 3 * 512 + tid) = v3;
        *(floatx4*)(xs4 + 4 * 512 + tid) = v4;
        __syncthreads();
        float accl[10][2];
#pragma unroll
        for (int m = 0; m < 10; ++m) { accl[m][0] = 0.f; accl[m][1] = 0.f; }
#pragma unroll
        for (int m = 0; m < 10; ++m)
#pragma unroll
          for (int c = 0; c < 4; ++c) {
            float4 x = xs4[m * 256 + c * 64 + lane];
#pragma unroll
            for (int r = 0; r < 2; ++r) {
              floatx4 ww = woutr[r][c];
              accl[m][r] += x.x * ww.x; accl[m][r] += x.y * ww.y;
              accl[m][r] += x.z * ww.z; accl[m][r] += x.w * ww.w;
            }
          }
#pragma unroll
        for (int m = 0; m < 10; ++m) {
          accl[m][0] = rowsum16(accl[m][0]);
          accl[m][1] = rowsum16(accl[m][1]);
        }
        if ((lane & 15) == 15) {
          int grp = lane >> 4;
#pragma unroll
          for (int m = 0; m < 10; ++m) {
            part[(wav * 4 + grp) * 20 + m * 2] = accl[m][0];
            part[(wav * 4 + grp) * 20 + m * 2 + 1] = accl[m][1];
          }
        }
        __syncthreads();
        if (tid < 160) {
          int mloc = tid >> 4, vloc = tid & 15;
          int wv = vloc >> 1, rowr = vloc & 1;
          float s = 0.f;
#pragma unroll
          for (int r = 0; r < 4; ++r) s += part[(wv * 4 + r) * 20 + mloc * 2 + rowr];
          int v = blk * 16 + vloc, mg = mbase + mloc;
          float lg = s + b_out[v];
          float e = rowsum16(expf(lg));
          if ((tid & 15) == 15) stcc(&expsum_part[mg * 256 + blk], e);
          float cv = lg; int ci = (mg % 5) * 4096 + v;   // flat cand idx kp*V+v
          float tv[5]; int ti5[5];
#pragma unroll
          for (int r5 = 0; r5 < 5; ++r5) {
            float mv = cv; int mi = ci;
#pragma unroll
            for (int off2 = 1; off2 < 16; off2 <<= 1) {
              float ov = __shfl_xor(mv, off2, 16);
              int oi = __shfl_xor(mi, off2, 16);
              if (ov > mv || (ov == mv && oi < mi)) { mv = ov; mi = oi; }
            }
            if (cv == mv && ci == mi) cv = -3.0e38f;   // pop winner
            tv[r5] = mv; ti5[r5] = mi;
          }
          if ((tid & 15) == 0) {
            int toff = (mg * 256 + blk) * 8;     // stride-8 padded record
            floatx4 tvv = {tv[0], tv[1], tv[2], tv[3]};
            intx4 tiv = {ti5[0], ti5[1], ti5[2], ti5[3]};
            stcc4(&top5v[toff], tvv); stcc(&top5v[toff + 4], tv[4]);
            stcc4i(&top5i[toff], tiv); stcci(&top5i[toff + 4], ti5[4]);
          }
        }
      }
    }
    gsync();

    // ---- phase M: 8 blocks merge candidates, publish next beam state ----
    if (blk < 8) {
      int b = blk;
      if (wav < 5) {
        int kp = wav;
        const float* ep = &expsum_part[(b * 5 + kp) * 256];
        floatx4 e4 = ldcc4(&ep[lane * 4]);
        // reproduce old per-64 grouping: ((p0+p1)+p2)+p3, then serial 64-term sum
        float tl = ((e4.x + e4.y) + e4.z) + e4.w;
        part[kp * 64 + lane] = tl;
        if (lane == 0) {
          float ssum = 0.f;
          for (int i = 0; i < 64; ++i) ssum += part[kp * 64 + i];
          s_scls[kp] = s_scores[b * 5 + kp] - logf(ssum);
        }
      }
      __syncthreads();
      float bv[5]; int bi5[5];
#pragma unroll
      for (int q = 0; q < 5; ++q) { bv[q] = -3.0e38f; bi5[q] = 0x7fffffff; }
      for (int e = wav * 160 + lane; e < wav * 160 + 160; e += 64) {
        int kp = e >> 8, blkc = e & 255;
        float base = s_scls[kp];
        int off = ((b * 5 + kp) * 256 + blkc) * 8;
        float tv[5]; int ti5[5];
        ldcc_top5(&top5v[off], &top5i[off], tv, ti5);
#pragma unroll
        for (int q = 0; q < 5; ++q) ins5(bv, bi5, tv[q] + base, ti5[q]);
      }
      float myv = 0.f; int myi = 0;
#pragma unroll
      for (int r = 0; r < 5; ++r) {
        float mv = bv[0]; int mi = bi5[0];
#pragma unroll
        for (int off2 = 1; off2 < 64; off2 <<= 1) {
          float ov = __shfl_xor(mv, off2, 64);
          int oi = __shfl_xor(mi, off2, 64);
          if (ov > mv || (ov == mv && oi < mi)) { mv = ov; mi = oi; }
        }
        if (bv[0] == mv && bi5[0] == mi) {   // owner pops
          bv[0] = bv[1]; bi5[0] = bi5[1]; bv[1] = bv[2]; bi5[1] = bi5[2];
          bv[2] = bv[3]; bi5[2] = bi5[3]; bv[3] = bv[4]; bi5[3] = bi5[4];
          bv[4] = -3.0e38f; bi5[4] = 0x7fffffff;
        }
        if (lane == r) { myv = mv; myi = mi; }
      }
      if (lane < 5) { wtv[wav * 5 + lane] = myv; wti[wav * 5 + lane] = myi; }
      __syncthreads();
      if (wav == 0) {
        float cv = (lane < 40) ? wtv[lane] : -3.0e38f;
        int ci = (lane < 40) ? wti[lane] : 0x7fffffff;
#pragma unroll
        for (int r = 0; r < 5; ++r) {
          float mv = cv; int mi = ci;
#pragma unroll
          for (int off2 = 1; off2 < 64; off2 <<= 1) {
            float ov = __shfl_xor(mv, off2, 64);
            int oi = __shfl_xor(mi, off2, 64);
            if (ov > mv || (ov == mv && oi < mi)) { mv = ov; mi = oi; }
          }
          if (cv == mv && ci == mi) cv = -3.0e38f;
          if (lane == r) { myv = mv; myi = mi; }
        }
        if (lane < 5) {
          int kp = myi >> 12, tok = myi & 4095;
          int isb = (tok == 0) ? 1 : 0;
          int pg = b * 5 + kp, slot = b * 5 + lane;
          stcc(&gscores[slot], myv); stcci(&gpar[slot], pg); stcci(&gblank[slot], isb);
          stcci(&gtokens[slot], isb ? s_tokens[pg] : tok);
          stcci(&glens[slot], s_lens[pg] + (isb ? 0 : 1));
        }
      }
    }
    gsync();
  }

  // final preds update (u = 128) + output
  if (tid < 40) {
    float sc; int ln, tk, pr, bl;
    ldcc_state(&gscores[tid], &glens[tid], &gtokens[tid], &gpar[tid], &gblank[tid],
               sc, ln, tk, pr, bl);
    s_scores[tid] = sc; s_lens[tid] = ln; s_tokens[tid] = tk;
    s_par[tid] = pr; s_blank[tid] = bl;
  }
  __syncthreads();
  if (blk < 4) preds_update(TSTEPS);
  gsync();

  if (blk == 0) {
    if (tid < 40) out[1033 + tid] = s_scores[tid] / (float)(s_lens[tid] + 1);
    if (tid < 8) {
      float bvn = -3.0e38f; int bk = 0;
      for (int k = 0; k < 5; ++k) {
        float n = s_scores[tid * 5 + k] / (float)(s_lens[tid * 5 + k] + 1);
        if (n > bvn) { bvn = n; bk = k; }
      }
      s_best[tid] = bk; s_maxn[tid] = bvn;
      out[1024 + tid] = (float)s_lens[tid * 5 + bk];
    }
    __syncthreads();
    if (tid == 0) {
      float s = 0.f;
      for (int b = 0; b < 8; ++b) s += expf(s_maxn[b]);
      out[1032] = s / 8.f;
    }
    for (int cI = tid; cI < 1024; cI += NT) {
      int b = cI >> 7, pos = cI & 127;
      out[cI] = (float)ldcci(&preds0[(b * 5 + s_best[b]) * 128 + pos]);  // final buf = preds0
    }
  }
}

// ---------- launch ----------

extern "C" void kernel_launch(void* const* d_in, const int* in_sizes, int n_in,
                              void* d_out, int out_size, void* d_ws, size_t ws_size,
                              hipStream_t stream) {
  const float* tn   = (const float*)d_in[0];
  const float* E    = (const float*)d_in[1];
  const float* Wih  = (const float*)d_in[2];
  const float* Whh  = (const float*)d_in[3];
  const float* bl   = (const float*)d_in[4];
  const float* Wtn  = (const float*)d_in[5];
  const float* Wpn  = (const float*)d_in[6];
  const float* bj   = (const float*)d_in[7];
  const float* Wout = (const float*)d_in[8];
  const float* bo   = (const float*)d_in[9];
  float* out = (float*)d_out;

  unsigned int* bar = (unsigned int*)d_ws;       // 2 KB: gsync[16] @ i*16,
                                                 // xcd reg @ 256+x, xbar @ 320+x*16
  float* w = (float*)d_ws + 512;
  size_t off = 0;
  float* tn_proj = w + off; off += 1048576;
  float* WpnT    = w + off; off += 1048576;
  float* WoutT   = w + off; off += 4194304;
  float* joint   = w + off; off += 40960;
  float* expsum  = w + off; off += 10240;    // 40 hyps x 256 blocks
  float* top5v   = w + off; off += 81920;    // 40 x 256 x 8 (stride-8 padded)
  float* h_pre0  = w + off; off += 40960;
  float* h_pre1  = w + off; off += 40960;
  float* c_pre0  = w + off; off += 40960;
  float* c_pre1  = w + off; off += 40960;
  float* h_new0  = w + off; off += 40960;
  float* h_new1  = w + off; off += 40960;
  float* c_new0  = w + off; off += 40960;
  float* c_new1  = w + off; off += 40960;
  float* xcdA    = w + off; off += 327680;   // 8 XCDs x [40][1024]
  float* xcdB    = w + off; off += 327680;
  float* gscores = w + off; off += 40;
  int* ib = (int*)(w + off);
  int* top5i   = ib; ib += 81920;
  int* preds0  = ib; ib += 5120;
  int* preds1  = ib; ib += 5120;
  int* glens   = ib; ib += 40;
  int* gtokens = ib; ib += 40;
  int* gpar    = ib; ib += 40;
  int* gblank  = ib; ib += 40;
  if (ws_size < (size_t)(512 + off + 92320) * 4) return;   // ~30.0 MB

  hipMemsetAsync(bar, 0, 2048, stream);
  hipMemsetAsync(preds0, 0, 5120 * sizeof(int), stream);
  k_transp<<<dim3(32, 32), 256, 0, stream>>>(Wpn, WpnT, 1024, 1024);
  k_transp<<<dim3(128, 32), 256, 0, stream>>>(Wout, WoutT, 1024, 4096);
  k_tnproj<<<256, 256, 0, stream>>>(tn, Wtn, tn_proj);

  void* args[] = { (void*)&E, (void*)&Wih, (void*)&Whh, (void*)&bl,
                   (void*)&tn_proj, (void*)&WpnT, (void*)&bj, (void*)&WoutT, (void*)&bo,
                   (void*)&h_pre0, (void*)&h_pre1, (void*)&c_pre0, (void*)&c_pre1,
                   (void*)&h_new0, (void*)&h_new1, (void*)&c_new0, (void*)&c_new1,
                   (void*)&joint, (void*)&expsum, (void*)&top5v, (void*)&top5i,
                   (void*)&preds0, (void*)&preds1, (void*)&gscores, (void*)&glens,
                   (void*)&gtokens, (void*)&gpar, (void*)&gblank,
                   (void*)&xcdA, (void*)&xcdB,
                   (void*)&bar, (void*)&out };
  hipLaunchCooperativeKernel((void*)k_beam, dim3(NB), dim3(NT), args, 0, stream);
}

// Round 10
// 12521.049 us; speedup vs baseline: 1.1515x; 1.1515x over previous
//
#include <hip/hip_runtime.h>
#include <math.h>

#define HH 1024
#define VV 4096
#define TSTEPS 128
#define NB 256
#define NT 512

typedef float  floatx4 __attribute__((ext_vector_type(4)));
typedef int    intx4   __attribute__((ext_vector_type(4)));

// ---------- helpers ----------

__device__ __forceinline__ float sigf(float x) { return 1.0f / (1.0f + expf(-x)); }

// sum across each 16-lane row via DPP; row total lands in lane (row*16+15).
__device__ __forceinline__ float rowsum16(float x) {
  x += __int_as_float(__builtin_amdgcn_update_dpp(0, __float_as_int(x), 0x111, 0xf, 0xf, true));
  x += __int_as_float(__builtin_amdgcn_update_dpp(0, __float_as_int(x), 0x112, 0xf, 0xf, true));
  x += __int_as_float(__builtin_amdgcn_update_dpp(0, __float_as_int(x), 0x114, 0xf, 0xf, true));
  x += __int_as_float(__builtin_amdgcn_update_dpp(0, __float_as_int(x), 0x118, 0xf, 0xf, true));
  return x;
}

// descending top-5 insert, tie -> lower flat index (matches jax.lax.top_k)
__device__ __forceinline__ void ins5(float* bv, int* bi, float v, int i) {
#pragma unroll
  for (int j = 0; j < 5; ++j) {
    if (v > bv[j] || (v == bv[j] && i < bi[j])) {
#pragma unroll
      for (int s = 4; s > j; --s) { bv[s] = bv[s - 1]; bi[s] = bi[s - 1]; }
      bv[j] = v; bi[j] = i;
      break;
    }
  }
}

// ---------- LLC-coherent (L1/L2-bypass) access: sc0 sc1 ----------
// All loads BLOCKING (waitcnt inside asm) - round-3 lesson.
// Round-8/9 lesson: neither trip-batching nor XCD-dedup helps; the dominant
// cost tracks BARRIER COUNT (poll storm on agent-scope atomics). This round
// attacks the barrier itself; staging stays as in the proven round-5 kernel.

__device__ __forceinline__ float ldcc(const float* p) {
  float v;
  asm volatile("global_load_dword %0, %1, off sc0 sc1\n\ts_waitcnt vmcnt(0)"
               : "=&v"(v) : "v"(p) : "memory");
  return v;
}
__device__ __forceinline__ int ldcci(const int* p) {
  int v;
  asm volatile("global_load_dword %0, %1, off sc0 sc1\n\ts_waitcnt vmcnt(0)"
               : "=&v"(v) : "v"(p) : "memory");
  return v;
}
__device__ __forceinline__ floatx4 ldcc4(const float* p) {
  floatx4 v;
  asm volatile("global_load_dwordx4 %0, %1, off sc0 sc1\n\ts_waitcnt vmcnt(0)"
               : "=&v"(v) : "v"(p) : "memory");
  return v;
}
__device__ __forceinline__ void stcc(float* p, float v) {
  asm volatile("global_store_dword %0, %1, off sc0 sc1" :: "v"(p), "v"(v) : "memory");
}
__device__ __forceinline__ void stcci(int* p, int v) {
  asm volatile("global_store_dword %0, %1, off sc0 sc1" :: "v"(p), "v"(v) : "memory");
}
__device__ __forceinline__ void stcc4(float* p, floatx4 v) {
  asm volatile("global_store_dwordx4 %0, %1, off sc0 sc1" :: "v"(p), "v"(v) : "memory");
}
__device__ __forceinline__ void stcc4i(int* p, intx4 v) {
  asm volatile("global_store_dwordx4 %0, %1, off sc0 sc1" :: "v"(p), "v"(v) : "memory");
}

// persistent-weight load: NORMAL cached load via asm volatile so the compiler
// can neither rematerialize nor sink it into the t-loop.
__device__ __forceinline__ void ldwt(floatx4& v, const float* p) {
  asm volatile("global_load_dwordx4 %0, %1, off\n\ts_waitcnt vmcnt(0)"
               : "=&v"(v) : "v"(p));
}

// 5 float4 coherent loads, one latency (single vmcnt inside the asm).
__device__ __forceinline__ void ldcc4x5(const float* p0, const float* p1, const float* p2,
                                        const float* p3, const float* p4,
                                        floatx4& v0, floatx4& v1, floatx4& v2,
                                        floatx4& v3, floatx4& v4) {
  asm volatile(
      "global_load_dwordx4 %0, %5, off sc0 sc1\n\t"
      "global_load_dwordx4 %1, %6, off sc0 sc1\n\t"
      "global_load_dwordx4 %2, %7, off sc0 sc1\n\t"
      "global_load_dwordx4 %3, %8, off sc0 sc1\n\t"
      "global_load_dwordx4 %4, %9, off sc0 sc1\n\t"
      "s_waitcnt vmcnt(0)"
      : "=&v"(v0), "=&v"(v1), "=&v"(v2), "=&v"(v3), "=&v"(v4)
      : "v"(p0), "v"(p1), "v"(p2), "v"(p3), "v"(p4)
      : "memory");
}

// three top5 records (each 5 floats + 5 ints, stride-8 padded), ONE latency.
__device__ __forceinline__ void ldcc_top5x3(
    const float* pv0, const int* pi0, const float* pv1, const int* pi1,
    const float* pv2, const int* pi2,
    float tv0[5], int ti0[5], float tv1[5], int ti1[5], float tv2[5], int ti2[5]) {
  floatx4 a0, a1, a2; float x0, x1, x2; intx4 b0, b1, b2; int y0, y1, y2;
  asm volatile(
      "global_load_dwordx4 %0, %12, off sc0 sc1\n\t"
      "global_load_dword   %1, %13, off sc0 sc1\n\t"
      "global_load_dwordx4 %2, %14, off sc0 sc1\n\t"
      "global_load_dword   %3, %15, off sc0 sc1\n\t"
      "global_load_dwordx4 %4, %16, off sc0 sc1\n\t"
      "global_load_dword   %5, %17, off sc0 sc1\n\t"
      "global_load_dwordx4 %6, %18, off sc0 sc1\n\t"
      "global_load_dword   %7, %19, off sc0 sc1\n\t"
      "global_load_dwordx4 %8, %20, off sc0 sc1\n\t"
      "global_load_dword   %9, %21, off sc0 sc1\n\t"
      "global_load_dwordx4 %10, %22, off sc0 sc1\n\t"
      "global_load_dword   %11, %23, off sc0 sc1\n\t"
      "s_waitcnt vmcnt(0)"
      : "=&v"(a0), "=&v"(x0), "=&v"(b0), "=&v"(y0),
        "=&v"(a1), "=&v"(x1), "=&v"(b1), "=&v"(y1),
        "=&v"(a2), "=&v"(x2), "=&v"(b2), "=&v"(y2)
      : "v"(pv0), "v"(pv0 + 4), "v"(pi0), "v"(pi0 + 4),
        "v"(pv1), "v"(pv1 + 4), "v"(pi1), "v"(pi1 + 4),
        "v"(pv2), "v"(pv2 + 4), "v"(pi2), "v"(pi2 + 4)
      : "memory");
  tv0[0] = a0.x; tv0[1] = a0.y; tv0[2] = a0.z; tv0[3] = a0.w; tv0[4] = x0;
  ti0[0] = b0.x; ti0[1] = b0.y; ti0[2] = b0.z; ti0[3] = b0.w; ti0[4] = y0;
  tv1[0] = a1.x; tv1[1] = a1.y; tv1[2] = a1.z; tv1[3] = a1.w; tv1[4] = x1;
  ti1[0] = b1.x; ti1[1] = b1.y; ti1[2] = b1.z; ti1[3] = b1.w; ti1[4] = y1;
  tv2[0] = a2.x; tv2[1] = a2.y; tv2[2] = a2.z; tv2[3] = a2.w; tv2[4] = x2;
  ti2[0] = b2.x; ti2[1] = b2.y; ti2[2] = b2.z; ti2[3] = b2.w; ti2[4] = y2;
}

// beam-state record (1 float + 4 ints), one latency.
__device__ __forceinline__ void ldcc_state(const float* ps, const int* pl, const int* pt,
                                           const int* pp, const int* pb,
                                           float& sc, int& ln, int& tk, int& pr, int& bl) {
  asm volatile(
      "global_load_dword %0, %5, off sc0 sc1\n\t"
      "global_load_dword %1, %6, off sc0 sc1\n\t"
      "global_load_dword %2, %7, off sc0 sc1\n\t"
      "global_load_dword %3, %8, off sc0 sc1\n\t"
      "global_load_dword %4, %9, off sc0 sc1\n\t"
      "s_waitcnt vmcnt(0)"
      : "=&v"(sc), "=&v"(ln), "=&v"(tk), "=&v"(pr), "=&v"(bl)
      : "v"(ps), "v"(pl), "v"(pt), "v"(pp), "v"(pb)
      : "memory");
}

// ---------- setup kernels ----------

// out[C][R] = in[R][C]
__global__ __launch_bounds__(256) void k_transp(const float* __restrict__ in,
                                                float* __restrict__ out, int R, int C) {
  __shared__ float tile[32][33];
  int c0 = blockIdx.x * 32, r0 = blockIdx.y * 32;
  int tx = threadIdx.x & 31, ty = threadIdx.x >> 5;
#pragma unroll
  for (int i = 0; i < 32; i += 8) tile[ty + i][tx] = in[(long)(r0 + ty + i) * C + c0 + tx];
  __syncthreads();
#pragma unroll
  for (int i = 0; i < 32; i += 8) out[(long)(c0 + ty + i) * R + r0 + tx] = tile[tx][ty + i];
}

// C[1024,1024] = A[1024,1024] @ B[1024,1024]   (tn_proj = tn_output @ W_tn)
__global__ __launch_bounds__(256) void k_tnproj(const float* __restrict__ A,
                                                const float* __restrict__ B,
                                                float* __restrict__ C) {
  __shared__ float As[64][20];
  __shared__ float Bs[16][68];
  int tid = threadIdx.x, blk = blockIdx.x;
  int bx = blk & 15, by = blk >> 4;
  int tx = tid & 15, ty = tid >> 4;
  float acc[4][4];
#pragma unroll
  for (int i = 0; i < 4; i++)
#pragma unroll
    for (int j = 0; j < 4; j++) acc[i][j] = 0.f;
  for (int k0 = 0; k0 < 1024; k0 += 16) {
    {
      int row = tid >> 2, q = tid & 3;
      float4 v = *(const float4*)&A[(long)(by * 64 + row) * 1024 + k0 + q * 4];
      As[row][q * 4] = v.x; As[row][q * 4 + 1] = v.y; As[row][q * 4 + 2] = v.z; As[row][q * 4 + 3] = v.w;
    }
    {
      int row = tid >> 4, q = tid & 15;
      float4 v = *(const float4*)&B[(long)(k0 + row) * 1024 + bx * 64 + q * 4];
      *(float4*)&Bs[row][q * 4] = v;
    }
    __syncthreads();
#pragma unroll
    for (int kk = 0; kk < 16; kk++) {
      float a0 = As[ty * 4][kk], a1 = As[ty * 4 + 1][kk], a2 = As[ty * 4 + 2][kk], a3 = As[ty * 4 + 3][kk];
      float4 b4 = *(const float4*)&Bs[kk][tx * 4];
      acc[0][0] += a0 * b4.x; acc[0][1] += a0 * b4.y; acc[0][2] += a0 * b4.z; acc[0][3] += a0 * b4.w;
      acc[1][0] += a1 * b4.x; acc[1][1] += a1 * b4.y; acc[1][2] += a1 * b4.z; acc[1][3] += a1 * b4.w;
      acc[2][0] += a2 * b4.x; acc[2][1] += a2 * b4.y; acc[2][2] += a2 * b4.z; acc[2][3] += a2 * b4.w;
      acc[3][0] += a3 * b4.x; acc[3][1] += a3 * b4.y; acc[3][2] += a3 * b4.z; acc[3][3] += a3 * b4.w;
    }
    __syncthreads();
  }
#pragma unroll
  for (int i = 0; i < 4; i++) {
    float4 v = make_float4(acc[i][0], acc[i][1], acc[i][2], acc[i][3]);
    *(float4*)&C[(long)(by * 64 + ty * 4 + i) * 1024 + bx * 64 + tx * 4] = v;
  }
}

// ---------- persistent megakernel ----------
// 256 blocks x 512 thr, cooperative. Round-5 structure (best: 12.54 ms) with
// a TWO-LEVEL barrier: arrivals on 16 spread counters; 16 leader blocks
// promote to one root; all blocks poll only the root with ONE thread each.
// Poll storm on the LLC drops ~15x vs 4096-poller round-5 barrier.

__global__ __launch_bounds__(NT, 1) void k_beam(
    const float* __restrict__ E, const float* __restrict__ Wih,
    const float* __restrict__ Whh, const float* __restrict__ b_lstm,
    const float* __restrict__ tn_proj, const float* __restrict__ WpnT,
    const float* __restrict__ b_joint, const float* __restrict__ WoutT,
    const float* __restrict__ b_out,
    float* __restrict__ h_pre0, float* __restrict__ h_pre1,
    float* __restrict__ c_pre0, float* __restrict__ c_pre1,
    float* __restrict__ h_new0, float* __restrict__ h_new1,
    float* __restrict__ c_new0, float* __restrict__ c_new1,
    float* __restrict__ joint, float* __restrict__ expsum_part,
    float* __restrict__ top5v, int* __restrict__ top5i,
    int* __restrict__ preds0, int* __restrict__ preds1,
    float* __restrict__ gscores, int* __restrict__ glens,
    int* __restrict__ gtokens, int* __restrict__ gpar, int* __restrict__ gblank,
    unsigned int* bar, float* __restrict__ out) {
  int tid = threadIdx.x, blk = blockIdx.x;
  int wav = tid >> 6, lane = tid & 63;

  __shared__ float xs[10240];           // 40 KB staging (union G/J/L)
  __shared__ float part[640];
  __shared__ float s_scores[40], s_scls[5];
  __shared__ int s_tokens[40], s_lens[40], s_par[40], s_blank[40];
  __shared__ float s_csel[160];         // prefetched c-state for G finish
  __shared__ float wtv[40];
  __shared__ int wti[40];
  __shared__ int s_best[8];
  __shared__ float s_maxn[8];
  float4* xs4 = (float4*)xs;

  // ---- persistent register-resident weights (asm-pinned loads) ----
  floatx4 wihr[2][4], whhr[2][4], wpnr[4], woutr[2][4];
#pragma unroll
  for (int rr = 0; rr < 2; ++rr) {
    int gr = wav * 2 + rr;
    int jg = blk * 4 + (gr >> 2), g = gr & 3;
#pragma unroll
    for (int c = 0; c < 4; ++c) {
      ldwt(wihr[rr][c], &Wih[(long)(g * HH + jg) * HH + c * 256 + lane * 4]);
      ldwt(whhr[rr][c], &Whh[(long)(g * HH + jg) * HH + c * 256 + lane * 4]);
    }
  }
  {
    int d = blk * 4 + (wav >> 1);       // two waves per d-row (m-halves)
#pragma unroll
    for (int c = 0; c < 4; ++c)
      ldwt(wpnr[c], &WpnT[(long)d * HH + c * 256 + lane * 4]);
  }
#pragma unroll
  for (int r = 0; r < 2; ++r) {
    int v = blk * 16 + wav * 2 + r;
#pragma unroll
    for (int c = 0; c < 4; ++c)
      ldwt(woutr[r][c], &WoutT[(long)v * HH + c * 256 + lane * 4]);
  }

  if (tid < 40) {
    s_scores[tid] = ((tid % 5) == 0) ? 0.f : -1e9f;
    s_tokens[tid] = 0; s_lens[tid] = 0; s_par[tid] = tid; s_blank[tid] = 1;
  }
  __syncthreads();

  unsigned int round = 0;
  // two-level fence-free barrier: vmcnt(0) drains write-through stores;
  // arrival on counter (blk&15)*16; leader blk<16 promotes its group to the
  // root at bar[256]; every block polls the root with one thread.
  auto gsync = [&]() {
    asm volatile("s_waitcnt vmcnt(0)" ::: "memory");
    __syncthreads();
    ++round;
    if (tid == 0) {
      __hip_atomic_fetch_add(&bar[(blk & 15) * 16], 1u, __ATOMIC_RELAXED, __HIP_MEMORY_SCOPE_AGENT);
      unsigned int tgt = round * 16u;
      if (blk < 16) {   // leader of group blk
        while (__hip_atomic_load(&bar[blk * 16], __ATOMIC_RELAXED, __HIP_MEMORY_SCOPE_AGENT) < tgt)
          __builtin_amdgcn_s_sleep(2);
        __hip_atomic_fetch_add(&bar[256], 1u, __ATOMIC_RELAXED, __HIP_MEMORY_SCOPE_AGENT);
      }
      while (__hip_atomic_load(&bar[256], __ATOMIC_RELAXED, __HIP_MEMORY_SCOPE_AGENT) < tgt)
        __builtin_amdgcn_s_sleep(2);
    }
    __syncthreads();
  };

  auto preds_update = [&](int u) {   // blk<4 only; final use
    const int* pip = ((u - 1) & 1) ? preds1 : preds0;
    int* pop = (u & 1) ? preds1 : preds0;
    int m0 = blk * 10;
    for (int cell = tid; cell < 1280; cell += NT) {
      int j = cell >> 7, pos = cell & 127, gj = m0 + j;
      int isb = s_blank[gj];
      int plen = s_lens[gj] - (isb ? 0 : 1);
      int v = ldcci(&pip[s_par[gj] * 128 + pos]);
      if (!isb && pos == plen) v = s_tokens[gj];
      stcci(&pop[gj * 128 + pos], v);
    }
  };

  for (int t = 0; t < TSTEPS; ++t) {
    const float* h_pre_in = (t & 1) ? h_pre1 : h_pre0;
    const float* h_new_in = (t & 1) ? h_new1 : h_new0;
    const float* c_pre_in = (t & 1) ? c_pre1 : c_pre0;
    const float* c_new_in = (t & 1) ? c_new1 : c_new0;
    float* h_pre_o = (t & 1) ? h_pre0 : h_pre1;
    float* h_new_o = (t & 1) ? h_new0 : h_new1;
    float* c_pre_o = (t & 1) ? c_pre0 : c_pre1;
    float* c_new_o = (t & 1) ? c_new0 : c_new1;

    if (t > 0) {   // load beam state published by M of step t-1
      if (tid < 40) {
        float sc; int ln, tk, pr, bl;
        ldcc_state(&gscores[tid], &glens[tid], &gtokens[tid], &gpar[tid], &gblank[tid],
                   sc, ln, tk, pr, bl);
        s_scores[tid] = sc; s_lens[tid] = ln; s_tokens[tid] = tk;
        s_par[tid] = pr; s_blank[tid] = bl;
      }
      __syncthreads();
      // prefetch c-state for all 8 G-chunks' finish sections (one latency)
      if (tid < 160) {
        int mg = tid >> 2, j = tid & 3;
        const float* cb = s_blank[mg] ? c_pre_in : c_new_in;
        s_csel[tid] = ldcc(&cb[(long)s_par[mg] * HH + blk * 4 + j]);
      }
      if (blk < 4) {   // preds shift: batched loads (one latency), then stores
        const int* pip = ((t - 1) & 1) ? preds1 : preds0;
        int* pop = (t & 1) ? preds1 : preds0;
        int m0b = blk * 10;
        int jA = tid >> 7, pA = tid & 127, gA = m0b + jA;
        int cB = tid + 512, jB = cB >> 7, pB = cB & 127, gB = m0b + jB;
        int cC = tid + 1024, jC = cC >> 7, pC = cC & 127, gC = m0b + jC;
        const int* aA = &pip[s_par[gA] * 128 + pA];
        const int* aB = &pip[s_par[gB] * 128 + pB];
        int vA, vB, vC = 0;
        if (tid < 256) {
          const int* aC = &pip[s_par[gC] * 128 + pC];
          asm volatile(
              "global_load_dword %0, %3, off sc0 sc1\n\t"
              "global_load_dword %1, %4, off sc0 sc1\n\t"
              "global_load_dword %2, %5, off sc0 sc1\n\t"
              "s_waitcnt vmcnt(0)"
              : "=&v"(vA), "=&v"(vB), "=&v"(vC)
              : "v"(aA), "v"(aB), "v"(aC) : "memory");
        } else {
          asm volatile(
              "global_load_dword %0, %2, off sc0 sc1\n\t"
              "global_load_dword %1, %3, off sc0 sc1\n\t"
              "s_waitcnt vmcnt(0)"
              : "=&v"(vA), "=&v"(vB)
              : "v"(aA), "v"(aB) : "memory");
        }
        {
          int isb = s_blank[gA], plen = s_lens[gA] - (isb ? 0 : 1);
          if (!isb && pA == plen) vA = s_tokens[gA];
          stcci(&pop[gA * 128 + pA], vA);
        }
        {
          int isb = s_blank[gB], plen = s_lens[gB] - (isb ? 0 : 1);
          if (!isb && pB == plen) vB = s_tokens[gB];
          stcci(&pop[gB * 128 + pB], vB);
        }
        if (tid < 256) {
          int isb = s_blank[gC], plen = s_lens[gC] - (isb ? 0 : 1);
          if (!isb && pC == plen) vC = s_tokens[gC];
          stcci(&pop[gC * 128 + pC], vC);
        }
      }
    }

    // ---- phase G: gates + cell for all 40 hyps, 8 staggered chunks of 5 ----
    {
      int mat = tid >> 8, k4f = (tid & 255) * 4;   // per-thread constant
      for (int cc = 0; cc < 8; ++cc) {
        int ch = (blk + cc) & 7;
        int mbase = ch * 5;
        if (mat == 0) {                 // E rows: read-only cached loads
#pragma unroll
          for (int i = 0; i < 5; ++i)
            xs4[i * 512 + tid] = *(const float4*)&E[(long)s_tokens[mbase + i] * HH + k4f];
        } else if (t == 0) {
          floatx4 z = {0.f, 0.f, 0.f, 0.f};
#pragma unroll
          for (int i = 0; i < 5; ++i) {
            *(floatx4*)(xs4 + i * 512 + tid) = z;
            if (blk == ch) stcc4(&h_pre_o[(long)(mbase + i) * HH + k4f], z);
          }
        } else {                        // h rows: LLC-coherent batched loads
          const float* p[5];
#pragma unroll
          for (int i = 0; i < 5; ++i) {
            int mg = mbase + i;
            const float* hb = s_blank[mg] ? h_pre_in : h_new_in;
            p[i] = &hb[(long)s_par[mg] * HH + k4f];
          }
          floatx4 v0, v1, v2, v3, v4;
          ldcc4x5(p[0], p[1], p[2], p[3], p[4], v0, v1, v2, v3, v4);
          *(floatx4*)(xs4 + 0 * 512 + tid) = v0;
          *(floatx4*)(xs4 + 1 * 512 + tid) = v1;
          *(floatx4*)(xs4 + 2 * 512 + tid) = v2;
          *(floatx4*)(xs4 + 3 * 512 + tid) = v3;
          *(floatx4*)(xs4 + 4 * 512 + tid) = v4;
          if (blk == ch) {
            stcc4(&h_pre_o[(long)(mbase + 0) * HH + k4f], v0);
            stcc4(&h_pre_o[(long)(mbase + 1) * HH + k4f], v1);
            stcc4(&h_pre_o[(long)(mbase + 2) * HH + k4f], v2);
            stcc4(&h_pre_o[(long)(mbase + 3) * HH + k4f], v3);
            stcc4(&h_pre_o[(long)(mbase + 4) * HH + k4f], v4);
          }
        }
        __syncthreads();
        float acc[5][2];
#pragma unroll
        for (int m = 0; m < 5; ++m) { acc[m][0] = 0.f; acc[m][1] = 0.f; }
#pragma unroll
        for (int m = 0; m < 5; ++m) {
#pragma unroll
          for (int c = 0; c < 4; ++c) {
            float4 x = xs4[m * 512 + c * 64 + lane];
#pragma unroll
            for (int rr = 0; rr < 2; ++rr) {
              floatx4 ww = wihr[rr][c];
              acc[m][rr] += x.x * ww.x; acc[m][rr] += x.y * ww.y;
              acc[m][rr] += x.z * ww.z; acc[m][rr] += x.w * ww.w;
            }
          }
#pragma unroll
          for (int c = 0; c < 4; ++c) {
            float4 x = xs4[m * 512 + 256 + c * 64 + lane];
#pragma unroll
            for (int rr = 0; rr < 2; ++rr) {
              floatx4 ww = whhr[rr][c];
              acc[m][rr] += x.x * ww.x; acc[m][rr] += x.y * ww.y;
              acc[m][rr] += x.z * ww.z; acc[m][rr] += x.w * ww.w;
            }
          }
        }
#pragma unroll
        for (int m = 0; m < 5; ++m) {
          acc[m][0] = rowsum16(acc[m][0]);
          acc[m][1] = rowsum16(acc[m][1]);
        }
        if ((lane & 15) == 15) {
          int grp = lane >> 4;
#pragma unroll
          for (int m = 0; m < 5; ++m) {
            part[(wav * 4 + grp) * 10 + m * 2] = acc[m][0];
            part[(wav * 4 + grp) * 10 + m * 2 + 1] = acc[m][1];
          }
        }
        __syncthreads();
        if (tid < 20) {
          int mloc = tid >> 2, j = tid & 3;
          int mg = mbase + mloc, jglob = blk * 4 + j;
          float gi = 0.f, gf = 0.f, gg = 0.f, go = 0.f;
#pragma unroll
          for (int r = 0; r < 4; ++r) {
            gi += part[((j * 2) * 4 + r) * 10 + mloc * 2];
            gf += part[((j * 2) * 4 + r) * 10 + mloc * 2 + 1];
            gg += part[((j * 2 + 1) * 4 + r) * 10 + mloc * 2];
            go += part[((j * 2 + 1) * 4 + r) * 10 + mloc * 2 + 1];
          }
          gi += b_lstm[jglob]; gf += b_lstm[HH + jglob];
          gg += b_lstm[2 * HH + jglob]; go += b_lstm[3 * HH + jglob];
          float csel = (t == 0) ? 0.f : s_csel[mg * 4 + j];
          float cn = sigf(gf) * csel + sigf(gi) * tanhf(gg);
          float hn = sigf(go) * tanhf(cn);
          long o = (long)mg * HH + jglob;
          stcc(&h_new_o[o], hn); stcc(&c_new_o[o], cn); stcc(&c_pre_o[o], csel);
        }
      }
    }
    gsync();

    // ---- phase J: joint = tanh(tn + h_new @ W_pn + b), 4 staggered chunks ----
    {
      int mrow = tid >> 8, k4f = (tid & 255) * 4;
      for (int cc = 0; cc < 4; ++cc) {
        int ch = (blk + cc) & 3;
        int mbase = ch * 10;
        floatx4 v0, v1, v2, v3, v4;
        ldcc4x5(&h_new_o[(long)(mbase + mrow + 0) * HH + k4f],
                &h_new_o[(long)(mbase + mrow + 2) * HH + k4f],
                &h_new_o[(long)(mbase + mrow + 4) * HH + k4f],
                &h_new_o[(long)(mbase + mrow + 6) * HH + k4f],
                &h_new_o[(long)(mbase + mrow + 8) * HH + k4f],
                v0, v1, v2, v3, v4);
        *(floatx4*)(xs4 + 0 * 512 + tid) = v0;
        *(floatx4*)(xs4 + 1 * 512 + tid) = v1;
        *(floatx4*)(xs4 + 2 * 512 + tid) = v2;
        *(floatx4*)(xs4 + 3 * 512 + tid) = v3;
        *(floatx4*)(xs4 + 4 * 512 + tid) = v4;
        __syncthreads();
        float accj[5];
#pragma unroll
        for (int m = 0; m < 5; ++m) accj[m] = 0.f;
        int mh = (wav & 1) * 5;
#pragma unroll
        for (int m = 0; m < 5; ++m) {
#pragma unroll
          for (int c = 0; c < 4; ++c) {
            float4 x = xs4[(mh + m) * 256 + c * 64 + lane];
            floatx4 ww = wpnr[c];
            accj[m] += x.x * ww.x; accj[m] += x.y * ww.y;
            accj[m] += x.z * ww.z; accj[m] += x.w * ww.w;
          }
        }
#pragma unroll
        for (int m = 0; m < 5; ++m) accj[m] = rowsum16(accj[m]);
        if ((lane & 15) == 15) {
          int grp = lane >> 4;
#pragma unroll
          for (int m = 0; m < 5; ++m) part[(wav * 4 + grp) * 5 + m] = accj[m];
        }
        __syncthreads();
        if (tid < 40) {
          int mloc = tid >> 2, d = tid & 3;
          int wv = d * 2 + (mloc >= 5 ? 1 : 0), m5 = mloc % 5;
          float s = 0.f;
#pragma unroll
          for (int r = 0; r < 4; ++r) s += part[(wv * 4 + r) * 5 + m5];
          int mg = mbase + mloc, dglob = blk * 4 + d, b = mg / 5;
          stcc(&joint[(long)mg * HH + dglob],
               tanhf(s + tn_proj[((long)b * TSTEPS + t) * HH + dglob] + b_joint[dglob]));
        }
      }
    }
    gsync();

    // ---- phase L: logits + per-(m,blk) exp-sum partial + local top-5 of 16 ----
    {
      int mrow = tid >> 8, k4f = (tid & 255) * 4;
      for (int cc = 0; cc < 4; ++cc) {
        int ch = (blk + cc) & 3;
        int mbase = ch * 10;
        floatx4 v0, v1, v2, v3, v4;
        ldcc4x5(&joint[(long)(mbase + mrow + 0) * HH + k4f],
                &joint[(long)(mbase + mrow + 2) * HH + k4f],
                &joint[(long)(mbase + mrow + 4) * HH + k4f],
                &joint[(long)(mbase + mrow + 6) * HH + k4f],
                &joint[(long)(mbase + mrow + 8) * HH + k4f],
                v0, v1, v2, v3, v4);
        *(floatx4*)(xs4 + 0 * 512 + tid) = v0;
        *(floatx4*)(xs4 + 1 * 512 + tid) = v1;
        *(floatx4*)(xs4 + 2 * 512 + tid) = v2;
        *(floatx4*)(xs4 + 3 * 512 + tid) = v3;
        *(floatx4*)(xs4 + 4 * 512 + tid) = v4;
        __syncthreads();
        float accl[10][2];
#pragma unroll
        for (int m = 0; m < 10; ++m) { accl[m][0] = 0.f; accl[m][1] = 0.f; }
#pragma unroll
        for (int m = 0; m < 10; ++m)
#pragma unroll
          for (int c = 0; c < 4; ++c) {
            float4 x = xs4[m * 256 + c * 64 + lane];
#pragma unroll
            for (int r = 0; r < 2; ++r) {
              floatx4 ww = woutr[r][c];
              accl[m][r] += x.x * ww.x; accl[m][r] += x.y * ww.y;
              accl[m][r] += x.z * ww.z; accl[m][r] += x.w * ww.w;
            }
          }
#pragma unroll
        for (int m = 0; m < 10; ++m) {
          accl[m][0] = rowsum16(accl[m][0]);
          accl[m][1] = rowsum16(accl[m][1]);
        }
        if ((lane & 15) == 15) {
          int grp = lane >> 4;
#pragma unroll
          for (int m = 0; m < 10; ++m) {
            part[(wav * 4 + grp) * 20 + m * 2] = accl[m][0];
            part[(wav * 4 + grp) * 20 + m * 2 + 1] = accl[m][1];
          }
        }
        __syncthreads();
        if (tid < 160) {
          int mloc = tid >> 4, vloc = tid & 15;
          int wv = vloc >> 1, rowr = vloc & 1;
          float s = 0.f;
#pragma unroll
          for (int r = 0; r < 4; ++r) s += part[(wv * 4 + r) * 20 + mloc * 2 + rowr];
          int v = blk * 16 + vloc, mg = mbase + mloc;
          float lg = s + b_out[v];
          float e = rowsum16(expf(lg));
          if ((tid & 15) == 15) stcc(&expsum_part[mg * 256 + blk], e);
          float cv = lg; int ci = (mg % 5) * 4096 + v;   // flat cand idx kp*V+v
          float tv[5]; int ti5[5];
#pragma unroll
          for (int r5 = 0; r5 < 5; ++r5) {
            float mv = cv; int mi = ci;
#pragma unroll
            for (int off2 = 1; off2 < 16; off2 <<= 1) {
              float ov = __shfl_xor(mv, off2, 16);
              int oi = __shfl_xor(mi, off2, 16);
              if (ov > mv || (ov == mv && oi < mi)) { mv = ov; mi = oi; }
            }
            if (cv == mv && ci == mi) cv = -3.0e38f;   // pop winner
            tv[r5] = mv; ti5[r5] = mi;
          }
          if ((tid & 15) == 0) {
            int toff = (mg * 256 + blk) * 8;     // stride-8 padded record
            floatx4 tvv = {tv[0], tv[1], tv[2], tv[3]};
            intx4 tiv = {ti5[0], ti5[1], ti5[2], ti5[3]};
            stcc4(&top5v[toff], tvv); stcc(&top5v[toff + 4], tv[4]);
            stcc4i(&top5i[toff], tiv); stcci(&top5i[toff + 4], ti5[4]);
          }
        }
      }
    }
    gsync();

    // ---- phase M: 8 blocks merge candidates (batched loads), publish state ----
    if (blk < 8) {
      int b = blk;
      if (wav < 5) {
        int kp = wav;
        const float* ep = &expsum_part[(b * 5 + kp) * 256];
        floatx4 e4 = ldcc4(&ep[lane * 4]);
        // reproduce old per-64 grouping: ((p0+p1)+p2)+p3, then serial 64-term sum
        float tl = ((e4.x + e4.y) + e4.z) + e4.w;
        part[kp * 64 + lane] = tl;
        if (lane == 0) {
          float ssum = 0.f;
          for (int i = 0; i < 64; ++i) ssum += part[kp * 64 + i];
          s_scls[kp] = s_scores[b * 5 + kp] - logf(ssum);
        }
      }
      __syncthreads();
      float bv[5]; int bi5[5];
#pragma unroll
      for (int q = 0; q < 5; ++q) { bv[q] = -3.0e38f; bi5[q] = 0x7fffffff; }
      int e0 = wav * 160 + lane;
      int kp0 = e0 >> 8, off0 = ((b * 5 + kp0) * 256 + (e0 & 255)) * 8;
      int e1 = e0 + 64;
      int kp1 = e1 >> 8, off1 = ((b * 5 + kp1) * 256 + (e1 & 255)) * 8;
      int e2 = e0 + 128;
      int kp2 = e2 >> 8, off2 = ((b * 5 + kp2) * 256 + (e2 & 255)) * 8;
      bool has2 = (lane < 32);
      int off2s = has2 ? off2 : off0;
      float tv0[5], tv1[5], tv2[5]; int ti0[5], ti1[5], ti2[5];
      ldcc_top5x3(&top5v[off0], &top5i[off0], &top5v[off1], &top5i[off1],
                  &top5v[off2s], &top5i[off2s], tv0, ti0, tv1, ti1, tv2, ti2);
      {
        float base = s_scls[kp0];
#pragma unroll
        for (int q = 0; q < 5; ++q) ins5(bv, bi5, tv0[q] + base, ti0[q]);
      }
      {
        float base = s_scls[kp1];
#pragma unroll
        for (int q = 0; q < 5; ++q) ins5(bv, bi5, tv1[q] + base, ti1[q]);
      }
      if (has2) {
        float base = s_scls[kp2];
#pragma unroll
        for (int q = 0; q < 5; ++q) ins5(bv, bi5, tv2[q] + base, ti2[q]);
      }
      float myv = 0.f; int myi = 0;
#pragma unroll
      for (int r = 0; r < 5; ++r) {
        float mv = bv[0]; int mi = bi5[0];
#pragma unroll
        for (int off2_ = 1; off2_ < 64; off2_ <<= 1) {
          float ov = __shfl_xor(mv, off2_, 64);
          int oi = __shfl_xor(mi, off2_, 64);
          if (ov > mv || (ov == mv && oi < mi)) { mv = ov; mi = oi; }
        }
        if (bv[0] == mv && bi5[0] == mi) {   // owner pops
          bv[0] = bv[1]; bi5[0] = bi5[1]; bv[1] = bv[2]; bi5[1] = bi5[2];
          bv[2] = bv[3]; bi5[2] = bi5[3]; bv[3] = bv[4]; bi5[3] = bi5[4];
          bv[4] = -3.0e38f; bi5[4] = 0x7fffffff;
        }
        if (lane == r) { myv = mv; myi = mi; }
      }
      if (lane < 5) { wtv[wav * 5 + lane] = myv; wti[wav * 5 + lane] = myi; }
      __syncthreads();
      if (wav == 0) {
        float cv = (lane < 40) ? wtv[lane] : -3.0e38f;
        int ci = (lane < 40) ? wti[lane] : 0x7fffffff;
#pragma unroll
        for (int r = 0; r < 5; ++r) {
          float mv = cv; int mi = ci;
#pragma unroll
          for (int off2_ = 1; off2_ < 64; off2_ <<= 1) {
            float ov = __shfl_xor(mv, off2_, 64);
            int oi = __shfl_xor(mi, off2_, 64);
            if (ov > mv || (ov == mv && oi < mi)) { mv = ov; mi = oi; }
          }
          if (cv == mv && ci == mi) cv = -3.0e38f;
          if (lane == r) { myv = mv; myi = mi; }
        }
        if (lane < 5) {
          int kp = myi >> 12, tok = myi & 4095;
          int isb = (tok == 0) ? 1 : 0;
          int pg = b * 5 + kp, slot = b * 5 + lane;
          stcc(&gscores[slot], myv); stcci(&gpar[slot], pg); stcci(&gblank[slot], isb);
          stcci(&gtokens[slot], isb ? s_tokens[pg] : tok);
          stcci(&glens[slot], s_lens[pg] + (isb ? 0 : 1));
        }
      }
    }
    gsync();
  }

  // final preds update (u = 128) + output
  if (tid < 40) {
    float sc; int ln, tk, pr, bl;
    ldcc_state(&gscores[tid], &glens[tid], &gtokens[tid], &gpar[tid], &gblank[tid],
               sc, ln, tk, pr, bl);
    s_scores[tid] = sc; s_lens[tid] = ln; s_tokens[tid] = tk;
    s_par[tid] = pr; s_blank[tid] = bl;
  }
  __syncthreads();
  if (blk < 4) preds_update(TSTEPS);
  gsync();

  if (blk == 0) {
    if (tid < 40) out[1033 + tid] = s_scores[tid] / (float)(s_lens[tid] + 1);
    if (tid < 8) {
      float bvn = -3.0e38f; int bk = 0;
      for (int k = 0; k < 5; ++k) {
        float n = s_scores[tid * 5 + k] / (float)(s_lens[tid * 5 + k] + 1);
        if (n > bvn) { bvn = n; bk = k; }
      }
      s_best[tid] = bk; s_maxn[tid] = bvn;
      out[1024 + tid] = (float)s_lens[tid * 5 + bk];
    }
    __syncthreads();
    if (tid == 0) {
      float s = 0.f;
      for (int b = 0; b < 8; ++b) s += expf(s_maxn[b]);
      out[1032] = s / 8.f;
    }
    for (int cI = tid; cI < 1024; cI += NT) {
      int b = cI >> 7, pos = cI & 127;
      out[cI] = (float)ldcci(&preds0[(b * 5 + s_best[b]) * 128 + pos]);  // final buf = preds0
    }
  }
}

// ---------- launch ----------

extern "C" void kernel_launch(void* const* d_in, const int* in_sizes, int n_in,
                              void* d_out, int out_size, void* d_ws, size_t ws_size,
                              hipStream_t stream) {
  const float* tn   = (const float*)d_in[0];
  const float* E    = (const float*)d_in[1];
  const float* Wih  = (const float*)d_in[2];
  const float* Whh  = (const float*)d_in[3];
  const float* bl   = (const float*)d_in[4];
  const float* Wtn  = (const float*)d_in[5];
  const float* Wpn  = (const float*)d_in[6];
  const float* bj   = (const float*)d_in[7];
  const float* Wout = (const float*)d_in[8];
  const float* bo   = (const float*)d_in[9];
  float* out = (float*)d_out;

  unsigned int* bar = (unsigned int*)d_ws;       // 2 KB: group ctrs @ g*16, root @ 256
  float* w = (float*)d_ws + 512;
  size_t off = 0;
  float* tn_proj = w + off; off += 1048576;
  float* WpnT    = w + off; off += 1048576;
  float* WoutT   = w + off; off += 4194304;
  float* joint   = w + off; off += 40960;
  float* expsum  = w + off; off += 10240;    // 40 hyps x 256 blocks
  float* top5v   = w + off; off += 81920;    // 40 x 256 x 8 (stride-8 padded)
  float* h_pre0  = w + off; off += 40960;
  float* h_pre1  = w + off; off += 40960;
  float* c_pre0  = w + off; off += 40960;
  float* c_pre1  = w + off; off += 40960;
  float* h_new0  = w + off; off += 40960;
  float* h_new1  = w + off; off += 40960;
  float* c_new0  = w + off; off += 40960;
  float* c_new1  = w + off; off += 40960;
  float* gscores = w + off; off += 40;
  int* ib = (int*)(w + off);
  int* top5i   = ib; ib += 81920;
  int* preds0  = ib; ib += 5120;
  int* preds1  = ib; ib += 5120;
  int* glens   = ib; ib += 40;
  int* gtokens = ib; ib += 40;
  int* gpar    = ib; ib += 40;
  int* gblank  = ib; ib += 40;
  if (ws_size < (size_t)(512 + off + 92320) * 4) return;   // ~27.4 MB

  hipMemsetAsync(bar, 0, 2048, stream);
  hipMemsetAsync(preds0, 0, 5120 * sizeof(int), stream);
  k_transp<<<dim3(32, 32), 256, 0, stream>>>(Wpn, WpnT, 1024, 1024);
  k_transp<<<dim3(128, 32), 256, 0, stream>>>(Wout, WoutT, 1024, 4096);
  k_tnproj<<<256, 256, 0, stream>>>(tn, Wtn, tn_proj);

  void* args[] = { (void*)&E, (void*)&Wih, (void*)&Whh, (void*)&bl,
                   (void*)&tn_proj, (void*)&WpnT, (void*)&bj, (void*)&WoutT, (void*)&bo,
                   (void*)&h_pre0, (void*)&h_pre1, (void*)&c_pre0, (void*)&c_pre1,
                   (void*)&h_new0, (void*)&h_new1, (void*)&c_new0, (void*)&c_new1,
                   (void*)&joint, (void*)&expsum, (void*)&top5v, (void*)&top5i,
                   (void*)&preds0, (void*)&preds1, (void*)&gscores, (void*)&glens,
                   (void*)&gtokens, (void*)&gpar, (void*)&gblank,
                   (void*)&bar, (void*)&out };
  hipLaunchCooperativeKernel((void*)k_beam, dim3(NB), dim3(NT), args, 0, stream);
}